// Round 1
// 174.963 us; speedup vs baseline: 1.0101x; 1.0101x over previous
//
#include <hip/hip_runtime.h>

// CPRPackedLinear: out(64x11008) = xperm[:, :1024] @ deq6(W_high) + xperm[:, 1024:] @ deq5(W_low) + bias
//
// Strategy: latency-bound previously (Occ 23%, VALU 16%, MFMA 4%). This version:
//  - 512-thread blocks (8 waves): waves split the two k-half-steps (q) per tile,
//    doubling waves/CU (10.7 -> 21.5) with zero extra partial-buffer traffic;
//    accumulators of the q=1 waves are folded into q=0 waves via LDS at epilogue.
//  - 1-deep register prefetch of next tile's packed ints + scale (register global
//    loads stay in flight across s_barrier; latency hides under dequant+MFMA).
//  - double-buffered LDS B-fragments -> single __syncthreads per k-tile (16 vs 32).

#define NFEAT 11008
#define KTOT  4096

typedef _Float16 half8 __attribute__((ext_vector_type(8)));
typedef float    f32x4 __attribute__((ext_vector_type(4)));

// ---------------- prep: x_perm -> fp16 in MFMA A-fragment layout ----------------
// xfrag flat idx = ((s*4 + mt)*64 + lane)*8 + j
//   holds x[m = mt*16 + (lane&15)][ col_indices[k = s*32 + (lane>>4)*8 + j] ]
__global__ __launch_bounds__(256) void prep_xfrag(const float* __restrict__ x,
                                                  const int* __restrict__ col,
                                                  _Float16* __restrict__ xfrag) {
    int idx = blockIdx.x * 256 + threadIdx.x;          // 0..262143
    int j  = idx & 7;
    int l  = (idx >> 3) & 63;
    int mt = (idx >> 9) & 3;
    int s  = idx >> 11;
    int k  = s * 32 + ((l >> 4) << 3) + j;
    int m  = mt * 16 + (l & 15);
    xfrag[idx] = (_Float16)x[m * KTOT + col[k]];
}

// ---------------- main GEMM ----------------
// grid.x = 172 (64-col tiles), grid.y = 4 (K chunks of 1024: chunk0=6bit high, 1..3=5bit low)
// block = 512 threads = 8 waves: wave w -> (mt = w&3, qm = w>>2)
__global__ __launch_bounds__(512) void gemm_kernel(const int* __restrict__ Wh,
                                                   const int* __restrict__ Wl,
                                                   const float* __restrict__ sh,
                                                   const float* __restrict__ sl,
                                                   const _Float16* __restrict__ xfrag,
                                                   float* __restrict__ dst,
                                                   int atomic_mode) {
    const int n0   = blockIdx.x * 64;
    const int kc   = blockIdx.y;
    const int tid  = threadIdx.x;
    const int lane = tid & 63;
    const int wave = tid >> 6;                          // 0..7

    // B fragments in LDS, fragment-ready, double-buffered: frag (nt, q), lane L at
    //   half-offset (((nt*2+q)*64 + L) + nt)*8  (the +nt*16B skew spreads ds_write_b128s)
    __shared__ _Float16 Wfrag[2][8 * 64 * 8 + 4 * 8];

    f32x4 acc[4];
#pragma unroll
    for (int i = 0; i < 4; ++i) acc[i] = (f32x4){0.f, 0.f, 0.f, 0.f};

    // ---- dequant role: thread owns (col = lane, k-group kg = wave) ----
    const int col  = lane;
    const int nt   = col >> 4;
    const int n_in = col & 15;
    const int kg   = wave;                              // 0..7, 8 k-rows each
    const int q_w  = kg >> 2, quad = kg & 3;
    const int woff = (((nt * 2 + q_w) * 64 + quad * 16 + n_in) + nt) * 8;

    // ---- MFMA role ----
    const int mt = wave & 3;                            // m-tile (16 rows)
    const int qm = wave >> 2;                           // which k-half-step of the tile

    auto mfma_step = [&](int t) {
        const int sg = kc * 32 + t * 2 + qm;            // global k-step of 32
        half8 a = *(const half8*)(xfrag + (((sg * 4 + mt) * 64 + lane) << 3));
        const _Float16* wf = Wfrag[t & 1];
#pragma unroll
        for (int j = 0; j < 4; ++j) {
            half8 b = *(const half8*)&wf[(((j * 2 + qm) * 64 + lane) + j) * 8];
            acc[j] = __builtin_amdgcn_mfma_f32_16x16x32_f16(a, b, acc[j], 0, 0, 0);
        }
    };

    if (kc == 0) {
        // ---- 6-bit region: 8 values from 6 packed ints (two groups of 4) ----
        const int*   base  = Wh + n0 + col;
        const float* sbase = sh + n0 + col;
        int c0, c1, c2, c3, c4, c5; float cs;
        {   // prefetch t=0: k = kg*8, G = k>>2 = kg*2
            const int* bp = base + 3 * (kg * 2) * NFEAT;
            c0 = bp[0];         c1 = bp[NFEAT];     c2 = bp[2 * NFEAT];
            c3 = bp[3 * NFEAT]; c4 = bp[4 * NFEAT]; c5 = bp[5 * NFEAT];
            cs = sbase[0];
        }
#pragma unroll 2
        for (int t = 0; t < 16; ++t) {
            int n_0 = 0, n_1 = 0, n_2 = 0, n_3 = 0, n_4 = 0, n_5 = 0; float ns = 0.f;
            if (t + 1 < 16) {                           // prefetch t+1
                const int G = (t + 1) * 16 + kg * 2;
                const int* bp = base + 3 * G * NFEAT;
                n_0 = bp[0];         n_1 = bp[NFEAT];     n_2 = bp[2 * NFEAT];
                n_3 = bp[3 * NFEAT]; n_4 = bp[4 * NFEAT]; n_5 = bp[5 * NFEAT];
                ns = sbase[((t + 1) >> 1) * NFEAT];
            }
            int v[8];
            v[0] = c0 & 63;
            v[1] = ((c0 >> 6) & 3) | ((c1 & 15) << 2);
            v[2] = ((c1 >> 4) & 15) | ((c2 & 3) << 4);
            v[3] = (c2 >> 2) & 63;
            v[4] = c3 & 63;
            v[5] = ((c3 >> 6) & 3) | ((c4 & 15) << 2);
            v[6] = ((c4 >> 4) & 15) | ((c5 & 3) << 4);
            v[7] = (c5 >> 2) & 63;
            half8 w;
#pragma unroll
            for (int j = 0; j < 8; ++j) w[j] = (_Float16)(((float)v[j] - 31.0f) * cs);
            *(half8*)&Wfrag[t & 1][woff] = w;
            __syncthreads();                            // buf[t&1] ready
            mfma_step(t);
            c0 = n_0; c1 = n_1; c2 = n_2; c3 = n_3; c4 = n_4; c5 = n_5; cs = ns;
        }
    } else {
        // ---- 5-bit region: 8 values from 5 packed ints ----
        const int*   base  = Wl + n0 + col;
        const float* sbase = sl + n0 + col;
        const int Gbase = (kc - 1) * 128;               // G = Gbase + t*8 + kg
        const int sbase_row = (kc - 1) * 8;             // scale row = sbase_row + (t>>1)
        int c0, c1, c2, c3, c4; float cs;
        {
            const int* bp = base + 5 * (Gbase + kg) * NFEAT;
            c0 = bp[0]; c1 = bp[NFEAT]; c2 = bp[2 * NFEAT];
            c3 = bp[3 * NFEAT]; c4 = bp[4 * NFEAT];
            cs = sbase[sbase_row * NFEAT];
        }
#pragma unroll 2
        for (int t = 0; t < 16; ++t) {
            int n_0 = 0, n_1 = 0, n_2 = 0, n_3 = 0, n_4 = 0; float ns = 0.f;
            if (t + 1 < 16) {
                const int* bp = base + 5 * (Gbase + (t + 1) * 8 + kg) * NFEAT;
                n_0 = bp[0]; n_1 = bp[NFEAT]; n_2 = bp[2 * NFEAT];
                n_3 = bp[3 * NFEAT]; n_4 = bp[4 * NFEAT];
                ns = sbase[(sbase_row + ((t + 1) >> 1)) * NFEAT];
            }
            int v[8];
            v[0] = c0 & 31;
            v[1] = ((c0 >> 5) & 7) | ((c1 & 3) << 3);
            v[2] = (c1 >> 2) & 31;
            v[3] = ((c1 >> 7) & 1) | ((c2 & 15) << 1);
            v[4] = ((c2 >> 4) & 15) | ((c3 & 1) << 4);
            v[5] = (c3 >> 1) & 31;
            v[6] = ((c3 >> 6) & 3) | ((c4 & 7) << 2);
            v[7] = (c4 >> 3) & 31;
            half8 w;
#pragma unroll
            for (int j = 0; j < 8; ++j) w[j] = (_Float16)(((float)v[j] - 15.0f) * cs);
            *(half8*)&Wfrag[t & 1][woff] = w;
            __syncthreads();
            mfma_step(t);
            c0 = n_0; c1 = n_1; c2 = n_2; c3 = n_3; c4 = n_4; cs = ns;
        }
    }

    // ---- epilogue: fold q=1 waves into q=0 waves via LDS, then store ----
    __syncthreads();                                    // all MFMA reads of Wfrag done
    float* red = (float*)&Wfrag[0][0];                  // 16*256 floats = 16 KB <= 16.5 KB
    if (wave >= 4) {
#pragma unroll
        for (int j = 0; j < 4; ++j)
#pragma unroll
            for (int r = 0; r < 4; ++r)
                red[(j * 4 + r) * 256 + (wave - 4) * 64 + lane] = acc[j][r];
    }
    __syncthreads();
    if (wave < 4) {
#pragma unroll
        for (int j = 0; j < 4; ++j)
#pragma unroll
            for (int r = 0; r < 4; ++r)
                acc[j][r] += red[(j * 4 + r) * 256 + wave * 64 + lane];

        // D row = wave*16 + (lane>>4)*4 + r, col = lane&15
        const int rb = wave * 16 + ((lane >> 4) << 2);
        const int cb = lane & 15;
        if (atomic_mode) {
#pragma unroll
            for (int j = 0; j < 4; ++j)
#pragma unroll
                for (int r = 0; r < 4; ++r)
                    atomicAdd(&dst[(rb + r) * NFEAT + n0 + j * 16 + cb], acc[j][r]);
        } else {
            float* base = dst + (size_t)kc * 64 * NFEAT;
#pragma unroll
            for (int j = 0; j < 4; ++j)
#pragma unroll
                for (int r = 0; r < 4; ++r)
                    base[(rb + r) * NFEAT + n0 + j * 16 + cb] = acc[j][r];
        }
    }
}

// ---------------- reduce: out = bias + sum_kc partial[kc] ----------------
__global__ __launch_bounds__(256) void reduce_out(const float* __restrict__ part,
                                                  const float* __restrict__ bias,
                                                  float* __restrict__ out) {
    const int idx = blockIdx.x * 256 + threadIdx.x;    // 0..176127 (float4 units)
    const int f   = idx * 4;
    const int n   = f % NFEAT;                          // NFEAT % 4 == 0 -> same row
    f32x4 a = *(const f32x4*)(part + f);
    f32x4 b = *(const f32x4*)(part + 704512 + f);
    f32x4 c = *(const f32x4*)(part + 2 * 704512 + f);
    f32x4 d = *(const f32x4*)(part + 3 * 704512 + f);
    f32x4 bi = *(const f32x4*)(bias + n);
    *(f32x4*)(out + f) = a + b + c + d + bi;
}

__global__ __launch_bounds__(256) void init_bias(const float* __restrict__ bias,
                                                 float* __restrict__ out) {
    const int idx = blockIdx.x * 256 + threadIdx.x;    // 0..704511
    out[idx] = bias[idx % NFEAT];
}

extern "C" void kernel_launch(void* const* d_in, const int* in_sizes, int n_in,
                              void* d_out, int out_size, void* d_ws, size_t ws_size,
                              hipStream_t stream) {
    const float* x    = (const float*)d_in[0];
    const int*   Wh   = (const int*)d_in[1];
    const int*   Wl   = (const int*)d_in[2];
    const float* sh   = (const float*)d_in[3];
    const float* sl   = (const float*)d_in[4];
    const int*   col  = (const int*)d_in[5];
    const float* bias = (const float*)d_in[6];
    float* out = (float*)d_out;

    _Float16* xfrag = (_Float16*)d_ws;                 // 512 KB
    const size_t xfrag_bytes = 64 * KTOT * sizeof(_Float16);
    const size_t part_bytes  = 4ull * 64 * NFEAT * sizeof(float);   // 11.27 MB

    prep_xfrag<<<1024, 256, 0, stream>>>(x, col, xfrag);

    dim3 grid(172, 4);
    if (ws_size >= xfrag_bytes + part_bytes) {
        float* part = (float*)((char*)d_ws + xfrag_bytes);
        gemm_kernel<<<grid, 512, 0, stream>>>(Wh, Wl, sh, sl, xfrag, part, 0);
        reduce_out<<<688, 256, 0, stream>>>(part, bias, out);
    } else {
        init_bias<<<2752, 256, 0, stream>>>(bias, out);
        gemm_kernel<<<grid, 512, 0, stream>>>(Wh, Wl, sh, sl, xfrag, out, 1);
    }
}